// Round 4
// baseline (352.638 us; speedup 1.0000x reference)
//
#include <hip/hip_runtime.h>
#include <math.h>

#define B_    8
#define AT_   96
#define NBR_  512
#define NANG_ 125
#define NF_   128
#define NB_   128
#define TN    32
#define NCHUNK 4
#define CROWS (NBR_ / NCHUNK)   // 128 neighbors per block
#define TSTRIDE 136             // bf16 elems per row (272 B, 16B-aligned)
#define JSTRIDE 132             // f32 elems per row (pad)

typedef __attribute__((ext_vector_type(8))) short bf16x8;
typedef __attribute__((ext_vector_type(4))) float f32x4;
typedef float f32x4u __attribute__((ext_vector_type(4), aligned(4)));
typedef __attribute__((ext_vector_type(4))) unsigned int u32x4;

// cheap bf16 convert: round-half-up, 2 VALU ops
__device__ __forceinline__ short f2bf(float f) {
    union { float f; unsigned u; } x; x.f = f;
    return (short)((x.u + 0x8000u) >> 16);
}

// pack two f32 -> two bf16 in one u32 (round-half-up), ~5 VALU ops
__device__ __forceinline__ unsigned pk2bf(float a, float b) {
    union { float f; unsigned u; } x, y; x.f = a; y.f = b;
    return ((x.u + 0x8000u) >> 16) | ((y.u + 0x8000u) & 0xffff0000u);
}

// shifted softplus on HW transcendentals:
// ssp(x) = ln2 * (log2(1 + exp2(x*log2e)) - 1); exact limits both ends.
__device__ __forceinline__ float sspf(float x) {
    float p = __builtin_amdgcn_exp2f(x * 1.44269504088896340736f);
    float l = __builtin_amdgcn_logf(1.0f + p);     // v_log_f32 = log2
    return 0.69314718055994530942f * l - 0.69314718055994530942f;
}

// Fused prep: blocks [0,192) compute y = x@Win for 4 rows each;
// blocks [192,320) pack W1/W2 into MFMA B-fragment order (bf16).
__global__ __launch_bounds__(128) void prep_kernel(
    const float* __restrict__ x, const float* __restrict__ Win,
    const float* __restrict__ W1, const float* __restrict__ W2,
    float* __restrict__ y, short* __restrict__ w1p, short* __restrict__ w2p)
{
    __shared__ float xs[4][NB_];
    int blk = blockIdx.x, tid = threadIdx.x;
    if (blk < 192) {
        int row0 = blk * 4;
        #pragma unroll
        for (int r = 0; r < 4; r++) xs[r][tid] = x[(row0 + r) * NB_ + tid];
        __syncthreads();
        float a0 = 0.f, a1 = 0.f, a2 = 0.f, a3 = 0.f;
        #pragma unroll 8
        for (int k = 0; k < NB_; k++) {
            float w = Win[k * NF_ + tid];
            a0 = fmaf(xs[0][k], w, a0);
            a1 = fmaf(xs[1][k], w, a1);
            a2 = fmaf(xs[2][k], w, a2);
            a3 = fmaf(xs[3][k], w, a3);
        }
        y[(row0 + 0) * NF_ + tid] = a0;
        y[(row0 + 1) * NF_ + tid] = a1;
        y[(row0 + 2) * NF_ + tid] = a2;
        y[(row0 + 3) * NF_ + tid] = a3;
    } else {
        int t = (blk - 192) * 128 + tid;   // [0, 16384)
        int j = t & 7, lane = (t >> 3) & 63, ks = (t >> 9) & 3, ct = t >> 11;
        int k = ks * 32 + (lane >> 4) * 8 + j;
        int n = ct * 16 + (lane & 15);
        w1p[t] = (k < NANG_) ? f2bf(W1[k * NF_ + n]) : (short)0;
        w2p[t] = f2bf(W2[k * NF_ + n]);
    }
}

// One block per (atom, nbr-chunk). Filternet MLP (bf16 MFMA) + conv +
// partial aggregation over 128 neighbors -> pagg.
__global__ __launch_bounds__(256) void triple_partial(
    const float* __restrict__ trip,
    const int* __restrict__ nbj, const int* __restrict__ nbk,
    const float* __restrict__ maskg,
    const float* __restrict__ b1g, const float* __restrict__ b2g,
    const float* __restrict__ y, const short* __restrict__ w1p,
    const short* __restrict__ w2p, float* __restrict__ pagg)
{
    __shared__ short ts[TN * TSTRIDE];
    __shared__ short hs[TN * TSTRIDE];
    __shared__ float yjk[TN * JSTRIDE];

    const int tid = threadIdx.x;
    const int wave = tid >> 6, lane = tid & 63;
    const int quad = lane >> 4, col = lane & 15;
    const int blk = blockIdx.x;            // bid*4 + c
    const int bid = blk >> 2, c = blk & 3;
    const int b = bid / AT_;

    const float* tpc = trip + (long)bid * NBR_ * NANG_ + (long)c * CROWS * NANG_;
    const int nb_base = bid * NBR_ + c * CROWS;

    const int ct0 = 2 * wave, ct1 = 2 * wave + 1;
    const int f0 = ct0 * 16 + col, f1 = ct1 * 16 + col;
    const float bias1_0 = b1g[f0], bias1_1 = b1g[f1];
    const float bias2_0 = b2g[f0], bias2_1 = b2g[f1];

    // staging roles (compile-time address math)
    const int srow = tid >> 3, schunk = tid & 7;   // ts: row, 16-feature chunk
    const int yrow = tid >> 3, ypart = tid & 7;    // yjk: row, 16-float part

    // loop-invariant W1 fragments, hoisted (32 VGPRs)
    bf16x8 w1f0[4], w1f1[4];
    #pragma unroll
    for (int ks = 0; ks < 4; ks++) {
        w1f0[ks] = *(const bf16x8*)&w1p[(ct0 * 4 + ks) * 512 + lane * 8];
        w1f1[ks] = *(const bf16x8*)&w1p[(ct1 * 4 + ks) * 512 + lane * 8];
    }

    float accw0 = 0.f, accw1 = 0.f;

    for (int nt = 0; nt < CROWS / TN; nt++) {
        const float* tp = tpc + nt * TN * NANG_;
        const int nrow0 = nb_base + nt * TN;

        // ---- issue all global loads for this tile up-front (prefetch) ----
        const float* rowp = tp + srow * NANG_ + schunk * 16;
        f32x4u v0, v1, v2, v3;
        if (schunk < 7) {
            v0 = *(const f32x4u*)(rowp + 0);
            v1 = *(const f32x4u*)(rowp + 4);
            v2 = *(const f32x4u*)(rowp + 8);
            v3 = *(const f32x4u*)(rowp + 12);
        } else {               // floats 112..124 valid; pad 125..127 with 0
            v0 = *(const f32x4u*)(rowp + 0);
            v1 = *(const f32x4u*)(rowp + 4);
            v2 = *(const f32x4u*)(rowp + 8);
            v3.x = rowp[12]; v3.y = 0.f; v3.z = 0.f; v3.w = 0.f;
        }

        const int jj = nbj[nrow0 + yrow], kk = nbk[nrow0 + yrow];
        const float m = maskg[nrow0 + yrow];
        const float* yjp = y + (b * AT_ + jj) * NF_ + ypart * 16;
        const float* ykp = y + (b * AT_ + kk) * NF_ + ypart * 16;
        f32x4 j0 = ((const f32x4*)yjp)[0], j1 = ((const f32x4*)yjp)[1];
        f32x4 j2 = ((const f32x4*)yjp)[2], j3 = ((const f32x4*)yjp)[3];
        f32x4 k0 = ((const f32x4*)ykp)[0], k1 = ((const f32x4*)ykp)[1];
        f32x4 k2 = ((const f32x4*)ykp)[2], k3 = ((const f32x4*)ykp)[3];

        __syncthreads();   // previous iteration's LDS reads complete

        // ---- ts tile: pack to bf16, two b128 writes, trivial addressing ----
        {
            u32x4 pA, pB;
            pA.x = pk2bf(v0.x, v0.y); pA.y = pk2bf(v0.z, v0.w);
            pA.z = pk2bf(v1.x, v1.y); pA.w = pk2bf(v1.z, v1.w);
            pB.x = pk2bf(v2.x, v2.y); pB.y = pk2bf(v2.z, v2.w);
            pB.z = pk2bf(v3.x, v3.y); pB.w = pk2bf(v3.z, v3.w);
            u32x4* dst = (u32x4*)&ts[srow * TSTRIDE + schunk * 16];
            dst[0] = pA;
            dst[1] = pB;
        }
        // ---- yjk = y_j * y_k * mask (fp32) ----
        {
            float* d = &yjk[yrow * JSTRIDE + ypart * 16];
            *(f32x4*)(d + 0)  = j0 * k0 * m;
            *(f32x4*)(d + 4)  = j1 * k1 * m;
            *(f32x4*)(d + 8)  = j2 * k2 * m;
            *(f32x4*)(d + 12) = j3 * k3 * m;
        }
        __syncthreads();

        // ---- GEMM1: H = ssp(T @ W1 + b1) ----
        f32x4 d00 = {0,0,0,0}, d01 = {0,0,0,0}, d10 = {0,0,0,0}, d11 = {0,0,0,0};
        #pragma unroll
        for (int ks = 0; ks < 4; ks++) {
            bf16x8 a0 = *(const bf16x8*)&ts[(     col) * TSTRIDE + ks * 32 + quad * 8];
            bf16x8 a1 = *(const bf16x8*)&ts[(16 + col) * TSTRIDE + ks * 32 + quad * 8];
            d00 = __builtin_amdgcn_mfma_f32_16x16x32_bf16(a0, w1f0[ks], d00, 0, 0, 0);
            d01 = __builtin_amdgcn_mfma_f32_16x16x32_bf16(a0, w1f1[ks], d01, 0, 0, 0);
            d10 = __builtin_amdgcn_mfma_f32_16x16x32_bf16(a1, w1f0[ks], d10, 0, 0, 0);
            d11 = __builtin_amdgcn_mfma_f32_16x16x32_bf16(a1, w1f1[ks], d11, 0, 0, 0);
        }
        #pragma unroll
        for (int r = 0; r < 4; r++) {
            int row0 = quad * 4 + r, row1 = 16 + quad * 4 + r;
            hs[row0 * TSTRIDE + f0] = f2bf(sspf(d00[r] + bias1_0));
            hs[row0 * TSTRIDE + f1] = f2bf(sspf(d01[r] + bias1_1));
            hs[row1 * TSTRIDE + f0] = f2bf(sspf(d10[r] + bias1_0));
            hs[row1 * TSTRIDE + f1] = f2bf(sspf(d11[r] + bias1_1));
        }
        __syncthreads();

        // ---- GEMM2 + fused conv + aggregation ----
        f32x4 e00 = {0,0,0,0}, e01 = {0,0,0,0}, e10 = {0,0,0,0}, e11 = {0,0,0,0};
        #pragma unroll
        for (int ks = 0; ks < 4; ks++) {
            bf16x8 a0 = *(const bf16x8*)&hs[(     col) * TSTRIDE + ks * 32 + quad * 8];
            bf16x8 a1 = *(const bf16x8*)&hs[(16 + col) * TSTRIDE + ks * 32 + quad * 8];
            bf16x8 w0 = *(const bf16x8*)&w2p[(ct0 * 4 + ks) * 512 + lane * 8];
            bf16x8 w1 = *(const bf16x8*)&w2p[(ct1 * 4 + ks) * 512 + lane * 8];
            e00 = __builtin_amdgcn_mfma_f32_16x16x32_bf16(a0, w0, e00, 0, 0, 0);
            e01 = __builtin_amdgcn_mfma_f32_16x16x32_bf16(a0, w1, e01, 0, 0, 0);
            e10 = __builtin_amdgcn_mfma_f32_16x16x32_bf16(a1, w0, e10, 0, 0, 0);
            e11 = __builtin_amdgcn_mfma_f32_16x16x32_bf16(a1, w1, e11, 0, 0, 0);
        }
        #pragma unroll
        for (int r = 0; r < 4; r++) {
            int row0 = quad * 4 + r, row1 = 16 + quad * 4 + r;
            accw0 += (e00[r] + bias2_0) * yjk[row0 * JSTRIDE + f0];
            accw1 += (e01[r] + bias2_1) * yjk[row0 * JSTRIDE + f1];
            accw0 += (e10[r] + bias2_0) * yjk[row1 * JSTRIDE + f0];
            accw1 += (e11[r] + bias2_1) * yjk[row1 * JSTRIDE + f1];
        }
    }

    // reduce partials across quads; write per-chunk partial aggregate
    accw0 += __shfl_xor(accw0, 16, 64);
    accw0 += __shfl_xor(accw0, 32, 64);
    accw1 += __shfl_xor(accw1, 16, 64);
    accw1 += __shfl_xor(accw1, 32, 64);
    if (quad == 0) {
        pagg[blk * NF_ + f0] = accw0;
        pagg[blk * NF_ + f1] = accw1;
    }
}

// Sum 4 partials, f2out (ssp), dense, residual.
__global__ __launch_bounds__(128) void finish_kernel(
    const float* __restrict__ x, const float* __restrict__ pagg,
    const float* __restrict__ Wf2, const float* __restrict__ bf2,
    const float* __restrict__ Wd, const float* __restrict__ bd,
    float* __restrict__ out)
{
    __shared__ float aggs[NF_];
    __shared__ float t1s[NF_];
    int bid = blockIdx.x, f = threadIdx.x;
    float a = pagg[(bid * 4 + 0) * NF_ + f] + pagg[(bid * 4 + 1) * NF_ + f]
            + pagg[(bid * 4 + 2) * NF_ + f] + pagg[(bid * 4 + 3) * NF_ + f];
    aggs[f] = a;
    __syncthreads();
    float acc = 0.f;
    #pragma unroll 8
    for (int k = 0; k < NF_; k++) acc = fmaf(aggs[k], Wf2[k * NB_ + f], acc);
    t1s[f] = sspf(acc + bf2[f]);
    __syncthreads();
    acc = 0.f;
    #pragma unroll 8
    for (int k = 0; k < NB_; k++) acc = fmaf(t1s[k], Wd[k * NB_ + f], acc);
    out[bid * NB_ + f] = x[bid * NB_ + f] + acc + bd[f];
}

extern "C" void kernel_launch(void* const* d_in, const int* in_sizes, int n_in,
                              void* d_out, int out_size, void* d_ws, size_t ws_size,
                              hipStream_t stream) {
    const float* x    = (const float*)d_in[0];
    const float* trip = (const float*)d_in[1];
    const int*   nbj  = (const int*)d_in[2];
    const int*   nbk  = (const int*)d_in[3];
    const float* mask = (const float*)d_in[4];
    const float* W1   = (const float*)d_in[5];
    const float* b1   = (const float*)d_in[6];
    const float* W2   = (const float*)d_in[7];
    const float* b2   = (const float*)d_in[8];
    const float* Win  = (const float*)d_in[9];
    const float* Wf2  = (const float*)d_in[10];
    const float* bf2  = (const float*)d_in[11];
    const float* Wd   = (const float*)d_in[12];
    const float* bd   = (const float*)d_in[13];
    float* out = (float*)d_out;

    char* ws = (char*)d_ws;
    float* y    = (float*)ws;                        // 393216 B
    short* w1p  = (short*)(ws + 393216);             // 32768 B
    short* w2p  = (short*)(ws + 393216 + 32768);     // 32768 B
    float* pagg = (float*)(ws + 393216 + 65536);     // 3072*128*4 = 1572864 B

    prep_kernel<<<320, 128, 0, stream>>>(x, Win, W1, W2, y, w1p, w2p);
    triple_partial<<<B_ * AT_ * NCHUNK, 256, 0, stream>>>(trip, nbj, nbk, mask,
        b1, b2, y, w1p, w2p, pagg);
    finish_kernel<<<B_ * AT_, 128, 0, stream>>>(x, pagg, Wf2, bf2, Wd, bd, out);
}

// Round 5
// 347.316 us; speedup vs baseline: 1.0153x; 1.0153x over previous
//
#include <hip/hip_runtime.h>
#include <math.h>

#define B_    8
#define AT_   96
#define NBR_  512
#define NANG_ 125
#define NF_   128
#define NB_   128
#define TN    32
#define NCHUNK 8
#define CROWS (NBR_ / NCHUNK)   // 64 neighbor rows per block, 2 tiles
#define TSTRIDE 136             // bf16 elems per row (272 B, 16B-aligned)

typedef __attribute__((ext_vector_type(8))) short bf16x8;
typedef __attribute__((ext_vector_type(4))) float f32x4;
typedef float f32x4u __attribute__((ext_vector_type(4), aligned(4)));
typedef __attribute__((ext_vector_type(4))) unsigned int u32x4;

// cheap bf16 convert: round-half-up
__device__ __forceinline__ short f2bf(float f) {
    union { float f; unsigned u; } x; x.f = f;
    return (short)((x.u + 0x8000u) >> 16);
}
__device__ __forceinline__ float bf2f(unsigned short h) {
    union { unsigned u; float f; } x; x.u = ((unsigned)h) << 16;
    return x.f;
}
// pack two f32 -> two bf16 in one u32 (round-half-up)
__device__ __forceinline__ unsigned pk2bf(float a, float b) {
    union { float f; unsigned u; } x, y; x.f = a; y.f = b;
    return ((x.u + 0x8000u) >> 16) | ((y.u + 0x8000u) & 0xffff0000u);
}

// shifted softplus on HW transcendentals:
// ssp(x) = ln2 * (log2(1 + exp2(x*log2e)) - 1); exact limits both ends.
__device__ __forceinline__ float sspf(float x) {
    float p = __builtin_amdgcn_exp2f(x * 1.44269504088896340736f);
    float l = __builtin_amdgcn_logf(1.0f + p);     // v_log_f32 = log2
    return 0.69314718055994530942f * l - 0.69314718055994530942f;
}

// Fused prep: blocks [0,192) compute y = x@Win for 4 rows each;
// blocks [192,320) pack W1/W2 into MFMA B-fragment order (bf16).
__global__ __launch_bounds__(128) void prep_kernel(
    const float* __restrict__ x, const float* __restrict__ Win,
    const float* __restrict__ W1, const float* __restrict__ W2,
    float* __restrict__ y, short* __restrict__ w1p, short* __restrict__ w2p)
{
    __shared__ float xs[4][NB_];
    int blk = blockIdx.x, tid = threadIdx.x;
    if (blk < 192) {
        int row0 = blk * 4;
        #pragma unroll
        for (int r = 0; r < 4; r++) xs[r][tid] = x[(row0 + r) * NB_ + tid];
        __syncthreads();
        float a0 = 0.f, a1 = 0.f, a2 = 0.f, a3 = 0.f;
        #pragma unroll 8
        for (int k = 0; k < NB_; k++) {
            float w = Win[k * NF_ + tid];
            a0 = fmaf(xs[0][k], w, a0);
            a1 = fmaf(xs[1][k], w, a1);
            a2 = fmaf(xs[2][k], w, a2);
            a3 = fmaf(xs[3][k], w, a3);
        }
        y[(row0 + 0) * NF_ + tid] = a0;
        y[(row0 + 1) * NF_ + tid] = a1;
        y[(row0 + 2) * NF_ + tid] = a2;
        y[(row0 + 3) * NF_ + tid] = a3;
    } else {
        int t = (blk - 192) * 128 + tid;   // [0, 16384)
        int j = t & 7, lane = (t >> 3) & 63, ks = (t >> 9) & 3, ct = t >> 11;
        int k = ks * 32 + (lane >> 4) * 8 + j;
        int n = ct * 16 + (lane & 15);
        w1p[t] = (k < NANG_) ? f2bf(W1[k * NF_ + n]) : (short)0;
        w2p[t] = f2bf(W2[k * NF_ + n]);
    }
}

// One block per (atom, nbr-chunk of 64). Filternet MLP (bf16 MFMA) + conv +
// partial aggregation -> pagg.
__global__ __launch_bounds__(256) void triple_partial(
    const float* __restrict__ trip,
    const int* __restrict__ nbj, const int* __restrict__ nbk,
    const float* __restrict__ maskg,
    const float* __restrict__ b1g, const float* __restrict__ b2g,
    const float* __restrict__ y, const short* __restrict__ w1p,
    const short* __restrict__ w2p, float* __restrict__ pagg)
{
    __shared__ short ts[TN * TSTRIDE];              // 8704 B
    __shared__ short hs[TN * TSTRIDE];              // 8704 B
    __shared__ unsigned short yjkb[TN * TSTRIDE];   // 8704 B (bf16 products)

    const int tid = threadIdx.x;
    const int wave = tid >> 6, lane = tid & 63;
    const int quad = lane >> 4, col = lane & 15;
    const int blk = blockIdx.x;            // bid*NCHUNK + c
    const int bid = blk >> 3, c = blk & 7;
    const int b = bid / AT_;

    const float* tpc = trip + (long)bid * NBR_ * NANG_ + (long)c * CROWS * NANG_;
    const int nb_base = bid * NBR_ + c * CROWS;

    const int ct0 = 2 * wave, ct1 = 2 * wave + 1;
    const int f0 = ct0 * 16 + col, f1 = ct1 * 16 + col;
    const float bias1_0 = b1g[f0], bias1_1 = b1g[f1];
    const float bias2_0 = b2g[f0], bias2_1 = b2g[f1];

    // staging roles (compile-time address math)
    const int srow = tid >> 3, schunk = tid & 7;   // row, 16-feature chunk

    // loop-invariant weight fragments, hoisted into registers (64 VGPRs)
    bf16x8 w1f0[4], w1f1[4], w2f0[4], w2f1[4];
    #pragma unroll
    for (int ks = 0; ks < 4; ks++) {
        w1f0[ks] = *(const bf16x8*)&w1p[(ct0 * 4 + ks) * 512 + lane * 8];
        w1f1[ks] = *(const bf16x8*)&w1p[(ct1 * 4 + ks) * 512 + lane * 8];
        w2f0[ks] = *(const bf16x8*)&w2p[(ct0 * 4 + ks) * 512 + lane * 8];
        w2f1[ks] = *(const bf16x8*)&w2p[(ct1 * 4 + ks) * 512 + lane * 8];
    }

    float accw0 = 0.f, accw1 = 0.f;

    for (int nt = 0; nt < CROWS / TN; nt++) {
        const float* tp = tpc + nt * TN * NANG_;
        const int nrow0 = nb_base + nt * TN;

        // ---- issue all global loads for this tile up-front (prefetch) ----
        const float* rowp = tp + srow * NANG_ + schunk * 16;
        f32x4u v0, v1, v2, v3;
        if (schunk < 7) {
            v0 = *(const f32x4u*)(rowp + 0);
            v1 = *(const f32x4u*)(rowp + 4);
            v2 = *(const f32x4u*)(rowp + 8);
            v3 = *(const f32x4u*)(rowp + 12);
        } else {               // floats 112..124 valid; pad 125..127 with 0
            v0 = *(const f32x4u*)(rowp + 0);
            v1 = *(const f32x4u*)(rowp + 4);
            v2 = *(const f32x4u*)(rowp + 8);
            v3.x = rowp[12]; v3.y = 0.f; v3.z = 0.f; v3.w = 0.f;
        }

        const int jj = nbj[nrow0 + srow], kk = nbk[nrow0 + srow];
        const float m = maskg[nrow0 + srow];
        const float* yjp = y + (b * AT_ + jj) * NF_ + schunk * 16;
        const float* ykp = y + (b * AT_ + kk) * NF_ + schunk * 16;
        f32x4 j0 = ((const f32x4*)yjp)[0], j1 = ((const f32x4*)yjp)[1];
        f32x4 j2 = ((const f32x4*)yjp)[2], j3 = ((const f32x4*)yjp)[3];
        f32x4 k0 = ((const f32x4*)ykp)[0], k1 = ((const f32x4*)ykp)[1];
        f32x4 k2 = ((const f32x4*)ykp)[2], k3 = ((const f32x4*)ykp)[3];

        __syncthreads();   // previous iteration's LDS reads complete

        // ---- ts tile: pack to bf16, two b128 writes ----
        {
            u32x4 pA, pB;
            pA.x = pk2bf(v0.x, v0.y); pA.y = pk2bf(v0.z, v0.w);
            pA.z = pk2bf(v1.x, v1.y); pA.w = pk2bf(v1.z, v1.w);
            pB.x = pk2bf(v2.x, v2.y); pB.y = pk2bf(v2.z, v2.w);
            pB.z = pk2bf(v3.x, v3.y); pB.w = pk2bf(v3.z, v3.w);
            u32x4* dst = (u32x4*)&ts[srow * TSTRIDE + schunk * 16];
            dst[0] = pA;
            dst[1] = pB;
        }
        // ---- yjk = y_j * y_k * mask, packed bf16, two b128 writes ----
        {
            f32x4 p0 = j0 * k0 * m, p1 = j1 * k1 * m;
            f32x4 p2 = j2 * k2 * m, p3 = j3 * k3 * m;
            u32x4 qA, qB;
            qA.x = pk2bf(p0.x, p0.y); qA.y = pk2bf(p0.z, p0.w);
            qA.z = pk2bf(p1.x, p1.y); qA.w = pk2bf(p1.z, p1.w);
            qB.x = pk2bf(p2.x, p2.y); qB.y = pk2bf(p2.z, p2.w);
            qB.z = pk2bf(p3.x, p3.y); qB.w = pk2bf(p3.z, p3.w);
            u32x4* dst = (u32x4*)&yjkb[srow * TSTRIDE + schunk * 16];
            dst[0] = qA;
            dst[1] = qB;
        }
        __syncthreads();

        // ---- GEMM1: H = ssp(T @ W1 + b1) ----
        f32x4 d00 = {0,0,0,0}, d01 = {0,0,0,0}, d10 = {0,0,0,0}, d11 = {0,0,0,0};
        #pragma unroll
        for (int ks = 0; ks < 4; ks++) {
            bf16x8 a0 = *(const bf16x8*)&ts[(     col) * TSTRIDE + ks * 32 + quad * 8];
            bf16x8 a1 = *(const bf16x8*)&ts[(16 + col) * TSTRIDE + ks * 32 + quad * 8];
            d00 = __builtin_amdgcn_mfma_f32_16x16x32_bf16(a0, w1f0[ks], d00, 0, 0, 0);
            d01 = __builtin_amdgcn_mfma_f32_16x16x32_bf16(a0, w1f1[ks], d01, 0, 0, 0);
            d10 = __builtin_amdgcn_mfma_f32_16x16x32_bf16(a1, w1f0[ks], d10, 0, 0, 0);
            d11 = __builtin_amdgcn_mfma_f32_16x16x32_bf16(a1, w1f1[ks], d11, 0, 0, 0);
        }
        #pragma unroll
        for (int r = 0; r < 4; r++) {
            int row0 = quad * 4 + r, row1 = 16 + quad * 4 + r;
            hs[row0 * TSTRIDE + f0] = f2bf(sspf(d00[r] + bias1_0));
            hs[row0 * TSTRIDE + f1] = f2bf(sspf(d01[r] + bias1_1));
            hs[row1 * TSTRIDE + f0] = f2bf(sspf(d10[r] + bias1_0));
            hs[row1 * TSTRIDE + f1] = f2bf(sspf(d11[r] + bias1_1));
        }
        __syncthreads();

        // ---- GEMM2 + fused conv + aggregation ----
        f32x4 e00 = {0,0,0,0}, e01 = {0,0,0,0}, e10 = {0,0,0,0}, e11 = {0,0,0,0};
        #pragma unroll
        for (int ks = 0; ks < 4; ks++) {
            bf16x8 a0 = *(const bf16x8*)&hs[(     col) * TSTRIDE + ks * 32 + quad * 8];
            bf16x8 a1 = *(const bf16x8*)&hs[(16 + col) * TSTRIDE + ks * 32 + quad * 8];
            e00 = __builtin_amdgcn_mfma_f32_16x16x32_bf16(a0, w2f0[ks], e00, 0, 0, 0);
            e01 = __builtin_amdgcn_mfma_f32_16x16x32_bf16(a0, w2f1[ks], e01, 0, 0, 0);
            e10 = __builtin_amdgcn_mfma_f32_16x16x32_bf16(a1, w2f0[ks], e10, 0, 0, 0);
            e11 = __builtin_amdgcn_mfma_f32_16x16x32_bf16(a1, w2f1[ks], e11, 0, 0, 0);
        }
        #pragma unroll
        for (int r = 0; r < 4; r++) {
            int row0 = quad * 4 + r, row1 = 16 + quad * 4 + r;
            accw0 += (e00[r] + bias2_0) * bf2f(yjkb[row0 * TSTRIDE + f0]);
            accw1 += (e01[r] + bias2_1) * bf2f(yjkb[row0 * TSTRIDE + f1]);
            accw0 += (e10[r] + bias2_0) * bf2f(yjkb[row1 * TSTRIDE + f0]);
            accw1 += (e11[r] + bias2_1) * bf2f(yjkb[row1 * TSTRIDE + f1]);
        }
    }

    // reduce partials across quads; write per-chunk partial aggregate
    accw0 += __shfl_xor(accw0, 16, 64);
    accw0 += __shfl_xor(accw0, 32, 64);
    accw1 += __shfl_xor(accw1, 16, 64);
    accw1 += __shfl_xor(accw1, 32, 64);
    if (quad == 0) {
        pagg[blk * NF_ + f0] = accw0;
        pagg[blk * NF_ + f1] = accw1;
    }
}

// Sum NCHUNK partials, f2out (ssp), dense, residual.
__global__ __launch_bounds__(128) void finish_kernel(
    const float* __restrict__ x, const float* __restrict__ pagg,
    const float* __restrict__ Wf2, const float* __restrict__ bf2,
    const float* __restrict__ Wd, const float* __restrict__ bd,
    float* __restrict__ out)
{
    __shared__ float aggs[NF_];
    __shared__ float t1s[NF_];
    int bid = blockIdx.x, f = threadIdx.x;
    float a = 0.f;
    #pragma unroll
    for (int c = 0; c < NCHUNK; c++) a += pagg[(bid * NCHUNK + c) * NF_ + f];
    aggs[f] = a;
    __syncthreads();
    float acc = 0.f;
    #pragma unroll 8
    for (int k = 0; k < NF_; k++) acc = fmaf(aggs[k], Wf2[k * NB_ + f], acc);
    t1s[f] = sspf(acc + bf2[f]);
    __syncthreads();
    acc = 0.f;
    #pragma unroll 8
    for (int k = 0; k < NB_; k++) acc = fmaf(t1s[k], Wd[k * NB_ + f], acc);
    out[bid * NB_ + f] = x[bid * NB_ + f] + acc + bd[f];
}

extern "C" void kernel_launch(void* const* d_in, const int* in_sizes, int n_in,
                              void* d_out, int out_size, void* d_ws, size_t ws_size,
                              hipStream_t stream) {
    const float* x    = (const float*)d_in[0];
    const float* trip = (const float*)d_in[1];
    const int*   nbj  = (const int*)d_in[2];
    const int*   nbk  = (const int*)d_in[3];
    const float* mask = (const float*)d_in[4];
    const float* W1   = (const float*)d_in[5];
    const float* b1   = (const float*)d_in[6];
    const float* W2   = (const float*)d_in[7];
    const float* b2   = (const float*)d_in[8];
    const float* Win  = (const float*)d_in[9];
    const float* Wf2  = (const float*)d_in[10];
    const float* bf2  = (const float*)d_in[11];
    const float* Wd   = (const float*)d_in[12];
    const float* bd   = (const float*)d_in[13];
    float* out = (float*)d_out;

    char* ws = (char*)d_ws;
    float* y    = (float*)ws;                        // 393216 B
    short* w1p  = (short*)(ws + 393216);             // 32768 B
    short* w2p  = (short*)(ws + 393216 + 32768);     // 32768 B
    float* pagg = (float*)(ws + 393216 + 65536);     // 6144*128*4 = 3145728 B

    prep_kernel<<<320, 128, 0, stream>>>(x, Win, W1, W2, y, w1p, w2p);
    triple_partial<<<B_ * AT_ * NCHUNK, 256, 0, stream>>>(trip, nbj, nbk, mask,
        b1, b2, y, w1p, w2p, pagg);
    finish_kernel<<<B_ * AT_, 128, 0, stream>>>(x, pagg, Wf2, bf2, Wd, bd, out);
}